// Round 1
// 320.844 us; speedup vs baseline: 2.1081x; 2.1081x over previous
//
#include <hip/hip_runtime.h>
#include <hip/hip_bf16.h>

// ---------------------------------------------------------------------------
// Cross-attention, b=2, n=2048, dim=1024, H=16, Dh=64. fp32 in, fp32 out.
// Pipeline: fp32->bf16 converts -> QKV MFMA GEMM (+Q/K/V^T scatter, Q pre-
// scaled by 1/8) -> MFMA flash attn (LDS-staged KV, double-buffered) ->
// out-proj MFMA GEMM -> fp32 store.
// Row layout: row = (s*2+b)*2048 + pos; s=0 half = out (slot 0).
//
// attn v2: K/V tiles staged to LDS once per block via global_load_lds(16B)
// with XOR-swizzled global source (linear LDS dest, rule: both-sides-or-
// neither), 2-phase double buffer (1 barrier/iter), 128 q-rows/block
// (32/wave), XCD-locality block remap so each (h,sb) KV pair lives on one
// XCD's L2 (8 groups x 512KB = 4MB/XCD).
// ---------------------------------------------------------------------------

typedef __attribute__((ext_vector_type(8))) short short8;   // 8 bf16 = 4 VGPR
typedef __attribute__((ext_vector_type(4))) float f32x4;    // MFMA 16x16 C/D

#define MFMA_BF16(a, b, c) __builtin_amdgcn_mfma_f32_16x16x32_bf16((a), (b), (c), 0, 0, 0)

__device__ __forceinline__ ushort f2bf(float f) {
    __hip_bfloat16 h = __float2bfloat16(f);
    return *reinterpret_cast<ushort*>(&h);
}

__device__ __forceinline__ void gload_lds16(const void* g, void* l) {
    __builtin_amdgcn_global_load_lds(
        (const __attribute__((address_space(1))) void*)g,
        (__attribute__((address_space(3))) void*)l, 16, 0, 0);
}

// ---------------------------------------------------------------------------
// fp32 -> bf16 convert (contiguous), 4 elems/thread
// ---------------------------------------------------------------------------
__global__ __launch_bounds__(256) void cvt_k(const float* __restrict__ in,
                                             ushort* __restrict__ out, int n) {
    const int i = (blockIdx.x * 256 + threadIdx.x) * 4;
    if (i >= n) return;
    float4 v = *(const float4*)(in + i);
    ushort4 o;
    o.x = f2bf(v.x); o.y = f2bf(v.y); o.z = f2bf(v.z); o.w = f2bf(v.w);
    *(ushort4*)(out + i) = o;
}

// ---------------------------------------------------------------------------
// fp32 transpose+convert  in[R][C] -> bf16 out[C][R]  (32x32 tiles)
// ---------------------------------------------------------------------------
__global__ __launch_bounds__(256) void transpose_cvt(const float* __restrict__ in,
                                                     ushort* __restrict__ out,
                                                     int R, int C) {
    __shared__ ushort tile[32][33];
    const int c0 = blockIdx.x * 32, r0 = blockIdx.y * 32;
    const int tx = threadIdx.x, ty = threadIdx.y;   // (32, 8)
#pragma unroll
    for (int i = 0; i < 4; ++i)
        tile[ty * 4 + i][tx] = f2bf(in[(size_t)(r0 + ty * 4 + i) * C + c0 + tx]);
    __syncthreads();
#pragma unroll
    for (int i = 0; i < 4; ++i)
        out[(size_t)(c0 + ty * 4 + i) * R + r0 + tx] = tile[tx][ty * 4 + i];
}

// ---------------------------------------------------------------------------
// QKV GEMM.  C[8192][3072] = Xb[8192][1024] @ Wqkv[1024][3072]
//   Epilogue scatters:  Q (pre-scaled 1/8), K -> [sb(4)][h(16)][n(2048)][64]
//                       V -> [sb(4)][h(16)][64][n(2048)]  (transposed)
// grid (24, 64), 256 threads (4 waves), tile 128x128, BK=32
// ---------------------------------------------------------------------------
__global__ __launch_bounds__(256) void qkv_gemm(const ushort* __restrict__ xb,
                                                const ushort* __restrict__ wt,
                                                ushort* __restrict__ qb,
                                                ushort* __restrict__ kb,
                                                ushort* __restrict__ vb) {
    __shared__ __align__(16) ushort As[128][40];
    __shared__ __align__(16) ushort Bs[128][40];

    const int n0 = blockIdx.x * 128;
    const int m0 = blockIdx.y * 128;
    const int t = threadIdx.x;
    const int lane = t & 63, w = t >> 6;
    const int wm = (w >> 1) * 64, wn = (w & 1) * 64;
    const int l16 = lane & 15, lq = lane >> 4;
    const int r = t >> 1, kc = (t & 1) * 16;

    f32x4 acc[4][4] = {};

    for (int k0 = 0; k0 < 1024; k0 += 32) {
        __syncthreads();
        {
            const ushort* p = xb + (size_t)(m0 + r) * 1024 + k0 + kc;
            short8 v0 = *(const short8*)p;
            short8 v1 = *(const short8*)(p + 8);
            *(short8*)&As[r][kc] = v0;
            *(short8*)&As[r][kc + 8] = v1;
            const ushort* q = wt + (size_t)(n0 + r) * 1024 + k0 + kc;
            short8 u0 = *(const short8*)q;
            short8 u1 = *(const short8*)(q + 8);
            *(short8*)&Bs[r][kc] = u0;
            *(short8*)&Bs[r][kc + 8] = u1;
        }
        __syncthreads();
        short8 a[4], b[4];
#pragma unroll
        for (int i = 0; i < 4; ++i) a[i] = *(const short8*)&As[wm + i * 16 + l16][lq * 8];
#pragma unroll
        for (int j = 0; j < 4; ++j) b[j] = *(const short8*)&Bs[wn + j * 16 + l16][lq * 8];
#pragma unroll
        for (int i = 0; i < 4; ++i)
#pragma unroll
            for (int j = 0; j < 4; ++j) acc[i][j] = MFMA_BF16(a[i], b[j], acc[i][j]);
    }

    const int which = (n0 >> 10);           // block-uniform: 0=Q 1=K 2=V
    const float qscale = (which == 0) ? 0.125f : 1.0f;

#pragma unroll
    for (int i = 0; i < 4; ++i) {
#pragma unroll
        for (int jj = 0; jj < 4; ++jj) {
#pragma unroll
            for (int rr = 0; rr < 4; ++rr) {
                const int m = m0 + wm + i * 16 + lq * 4 + rr;   // 0..8191
                const int nc = n0 + wn + jj * 16 + l16;         // 0..3071
                const ushort bv = f2bf(acc[i][jj][rr] * qscale);
                const int s = m >> 12;          // 0 = x-half, 1 = x1-half
                const int mm = m & 4095;        // b*2048+pos
                const int rem = nc & 1023;
                const int h = rem >> 6, d = rem & 63;
                const int sb = (s << 1) | (mm >> 11);
                const int pos = mm & 2047;
                const size_t bh = (size_t)(sb * 16 + h);
                if (which == 0)      qb[(bh * 2048 + pos) * 64 + d] = bv;
                else if (which == 1) kb[(bh * 2048 + pos) * 64 + d] = bv;
                else                 vb[(bh * 64 + d) * 2048 + pos] = bv;
            }
        }
    }
}

// ---------------------------------------------------------------------------
// MFMA flash cross-attention v2.
// grid 1024 (remapped to (qt,h,sb)), 256 threads (4 waves). Block owns 128
// q-rows (wave: 32). KVBLK=64. K-tile (64x128B) + V^T-tile (64x128B) staged
// to LDS once per block, double-buffered, global_load_lds w=16 with
// XOR-swizzled SOURCE (LDS linear) so ds_read_b128 frags are conflict-free.
// Per iter: stage(next) -> 16 QK MFMA -> exp -> P-LDS (swizzled, same-wave
// waitcnt RAW) -> 4 ones-MFMA + 16 PV MFMA -> syncthreads (drains vmcnt).
// ---------------------------------------------------------------------------
__global__ __launch_bounds__(256, 4) void attn_k(const ushort* __restrict__ qb,
                                                 const ushort* __restrict__ kb,
                                                 const ushort* __restrict__ vb,
                                                 ushort* __restrict__ ob) {
    __shared__ __align__(16) ushort Ks[2][4096];   // 2 x 8KB  (64 rows x 128B)
    __shared__ __align__(16) ushort Vs[2][4096];   // 2 x 8KB  (V^T: 64 d-rows x 128B)
    __shared__ __align__(16) ushort Pt[4][1024];   // per-wave 16x64 bf16, swizzled

    const int t = threadIdx.x, lane = t & 63, w = t >> 6;
    const int l16 = lane & 15, lq = lane >> 4;

    // XCD-locality remap: all 16 q-tiles of one (h,sb) on one XCD (lid%8).
    const int lid = blockIdx.x;                 // 0..1023
    const int xcd = lid & 7, kk = lid >> 3;     // kk: 0..127
    const int qt = kk & 15;
    const int g = xcd + ((kk >> 4) << 3);       // kv-group 0..63
    const int h = g & 15, sb = g >> 4;
    const int s = sb >> 1, bb = sb & 1;
    const int kvsb = ((1 - s) << 1) | bb;
    const int q0 = qt * 128 + w * 32;

    const ushort* qp = qb + (size_t)(sb * 16 + h) * 2048 * 64;
    const char* kp = (const char*)(kb + (size_t)(kvsb * 16 + h) * 2048 * 64);
    const char* vp = (const char*)(vb + (size_t)(kvsb * 16 + h) * 64 * 2048);

    // Q fragments: 2 q-subtiles x 2 K-chunks (Q pre-scaled by 1/8 upstream)
    short8 aq[2][2];
#pragma unroll
    for (int u = 0; u < 2; ++u)
#pragma unroll
        for (int c = 0; c < 2; ++c)
            aq[u][c] = *(const short8*)(qp + (size_t)(q0 + u * 16 + l16) * 64 + c * 32 + lq * 8);

    short8 ones;
#pragma unroll
    for (int j = 0; j < 8; ++j) ones[j] = (short)0x3F80;   // bf16 1.0

    f32x4 o_acc[2][4] = {};   // [u][dt]: row=lq*4+r (q), col=dt*16+l16 (d)
    f32x4 l_acc[2] = {};      // [u]: row sums

    // stage one 64-key tile (K: contiguous 8KB; V^T: 64 rows stride 4096B).
    // LDS dest linear (base + lane*16); source XOR-pre-swizzled: for linear
    // LDS byte off, row=off>>7 and src_off = off ^ ((row&7)<<4).
    const int swl = ((lane >> 3) & 7) << 4;           // (row&7)<<4 for this lane
    auto stage = [&](int buf, int key0) {
#pragma unroll
        for (int i = 0; i < 2; ++i) {
            const int ch = w * 2 + i;                  // 1KB chunk 0..7
            const int off = ch * 1024 + lane * 16;     // linear LDS byte offset
            gload_lds16(kp + (size_t)key0 * 128 + (off ^ swl),
                        (char*)&Ks[buf][0] + ch * 1024);
            const int rd = ch * 8 + (lane >> 3);       // V^T d-row 0..63
            const int cb = (lane & 7) * 16;            // col byte within row
            gload_lds16(vp + (size_t)rd * 4096 + (size_t)key0 * 2 + (cb ^ swl),
                        (char*)&Vs[buf][0] + ch * 1024);
        }
    };

    stage(0, 0);
    __syncthreads();   // implicit vmcnt(0) drain before barrier

    char* Pw = (char*)&Pt[w][0];

    for (int tt = 0; tt < 32; ++tt) {
        const int cur = tt & 1;
        if (tt < 31) stage(cur ^ 1, (tt + 1) * 64);   // overlap with compute

        const char* Kc = (const char*)&Ks[cur][0];
        const char* Vc = (const char*)&Vs[cur][0];

        // QK^T: 4 key-subtiles x 2 q-subtiles
        f32x4 sc0[4] = {}, sc1[4] = {};
#pragma unroll
        for (int j = 0; j < 4; ++j) {
            const int row = j * 16 + l16;
            const int swr = (row & 7) << 4;
            short8 k0 = *(const short8*)(Kc + row * 128 + ((lq * 16) ^ swr));
            short8 k1 = *(const short8*)(Kc + row * 128 + ((64 + lq * 16) ^ swr));
            sc0[j] = MFMA_BF16(aq[0][0], k0, sc0[j]);
            sc0[j] = MFMA_BF16(aq[0][1], k1, sc0[j]);
            sc1[j] = MFMA_BF16(aq[1][0], k0, sc1[j]);
            sc1[j] = MFMA_BF16(aq[1][1], k1, sc1[j]);
        }

        short8 ap[2][2];
        // q-subtile 0: p = exp(s) -> swizzled P-LDS -> A-frag read
#pragma unroll
        for (int j = 0; j < 4; ++j)
#pragma unroll
            for (int r2 = 0; r2 < 4; ++r2) {
                const int row = lq * 4 + r2;
                *(ushort*)(Pw + row * 128 + ((j * 32 + l16 * 2) ^ ((row & 7) << 4))) =
                    f2bf(__expf(sc0[j][r2]));
            }
        asm volatile("s_waitcnt lgkmcnt(0)" ::: "memory");   // same-wave RAW
        {
            const int swr = (l16 & 7) << 4;
            ap[0][0] = *(const short8*)(Pw + l16 * 128 + ((lq * 16) ^ swr));
            ap[0][1] = *(const short8*)(Pw + l16 * 128 + ((64 + lq * 16) ^ swr));
        }
        asm volatile("s_waitcnt lgkmcnt(0)" ::: "memory");   // reads landed (WAR safety)
        // q-subtile 1 reuses the same P scratch
#pragma unroll
        for (int j = 0; j < 4; ++j)
#pragma unroll
            for (int r2 = 0; r2 < 4; ++r2) {
                const int row = lq * 4 + r2;
                *(ushort*)(Pw + row * 128 + ((j * 32 + l16 * 2) ^ ((row & 7) << 4))) =
                    f2bf(__expf(sc1[j][r2]));
            }
        asm volatile("s_waitcnt lgkmcnt(0)" ::: "memory");
        {
            const int swr = (l16 & 7) << 4;
            ap[1][0] = *(const short8*)(Pw + l16 * 128 + ((lq * 16) ^ swr));
            ap[1][1] = *(const short8*)(Pw + l16 * 128 + ((64 + lq * 16) ^ swr));
        }

        l_acc[0] = MFMA_BF16(ap[0][0], ones, l_acc[0]);
        l_acc[0] = MFMA_BF16(ap[0][1], ones, l_acc[0]);
        l_acc[1] = MFMA_BF16(ap[1][0], ones, l_acc[1]);
        l_acc[1] = MFMA_BF16(ap[1][1], ones, l_acc[1]);
#pragma unroll
        for (int dt = 0; dt < 4; ++dt) {
            const int row = dt * 16 + l16;
            const int swr = (row & 7) << 4;
            short8 v0 = *(const short8*)(Vc + row * 128 + ((lq * 16) ^ swr));
            short8 v1 = *(const short8*)(Vc + row * 128 + ((64 + lq * 16) ^ swr));
            o_acc[0][dt] = MFMA_BF16(ap[0][0], v0, o_acc[0][dt]);
            o_acc[0][dt] = MFMA_BF16(ap[0][1], v1, o_acc[0][dt]);
            o_acc[1][dt] = MFMA_BF16(ap[1][0], v0, o_acc[1][dt]);
            o_acc[1][dt] = MFMA_BF16(ap[1][1], v1, o_acc[1][dt]);
        }

        __syncthreads();   // drains vmcnt(0): next tile staged + frag reads done
    }

#pragma unroll
    for (int u = 0; u < 2; ++u) {
        float inv[4];
#pragma unroll
        for (int r2 = 0; r2 < 4; ++r2) inv[r2] = 1.f / l_acc[u][r2];
#pragma unroll
        for (int dt = 0; dt < 4; ++dt)
#pragma unroll
            for (int r2 = 0; r2 < 4; ++r2)
                ob[(size_t)(sb * 2048 + q0 + u * 16 + lq * 4 + r2) * 1024 + h * 64 + dt * 16 + l16] =
                    f2bf(o_acc[u][dt][r2] * inv[r2]);
    }
}

// ---------------------------------------------------------------------------
// Out projection. OUT[8192][1024] = O[8192][1024] @ Wout + bias.
// FP32 stores to d_out. grid (8, 64), 256 threads.
// ---------------------------------------------------------------------------
__global__ __launch_bounds__(256) void out_gemm(const ushort* __restrict__ ob,
                                                const ushort* __restrict__ wot,
                                                const float* __restrict__ bias,
                                                float* __restrict__ out) {
    __shared__ __align__(16) ushort As[128][40];
    __shared__ __align__(16) ushort Bs[128][40];

    const int n0 = blockIdx.x * 128;
    const int m0 = blockIdx.y * 128;
    const int t = threadIdx.x;
    const int lane = t & 63, w = t >> 6;
    const int wm = (w >> 1) * 64, wn = (w & 1) * 64;
    const int l16 = lane & 15, lq = lane >> 4;
    const int r = t >> 1, kc = (t & 1) * 16;

    f32x4 acc[4][4] = {};

    for (int k0 = 0; k0 < 1024; k0 += 32) {
        __syncthreads();
        {
            const ushort* p = ob + (size_t)(m0 + r) * 1024 + k0 + kc;
            short8 v0 = *(const short8*)p;
            short8 v1 = *(const short8*)(p + 8);
            *(short8*)&As[r][kc] = v0;
            *(short8*)&As[r][kc + 8] = v1;
            const ushort* q = wot + (size_t)(n0 + r) * 1024 + k0 + kc;
            short8 u0 = *(const short8*)q;
            short8 u1 = *(const short8*)(q + 8);
            *(short8*)&Bs[r][kc] = u0;
            *(short8*)&Bs[r][kc + 8] = u1;
        }
        __syncthreads();
        short8 a[4], b[4];
#pragma unroll
        for (int i = 0; i < 4; ++i) a[i] = *(const short8*)&As[wm + i * 16 + l16][lq * 8];
#pragma unroll
        for (int j = 0; j < 4; ++j) b[j] = *(const short8*)&Bs[wn + j * 16 + l16][lq * 8];
#pragma unroll
        for (int i = 0; i < 4; ++i)
#pragma unroll
            for (int j = 0; j < 4; ++j) acc[i][j] = MFMA_BF16(a[i], b[j], acc[i][j]);
    }

    float biasf[4];
#pragma unroll
    for (int jj = 0; jj < 4; ++jj) biasf[jj] = bias[n0 + wn + jj * 16 + l16];

#pragma unroll
    for (int i = 0; i < 4; ++i)
#pragma unroll
        for (int jj = 0; jj < 4; ++jj)
#pragma unroll
            for (int rr = 0; rr < 4; ++rr) {
                const int m = m0 + wm + i * 16 + lq * 4 + rr;
                const int nc = n0 + wn + jj * 16 + l16;
                out[(size_t)m * 1024 + nc] = acc[i][jj][rr] + biasf[jj];   // fp32 store
            }
}

// ---------------------------------------------------------------------------
extern "C" void kernel_launch(void* const* d_in, const int* in_sizes, int n_in,
                              void* d_out, int out_size, void* d_ws, size_t ws_size,
                              hipStream_t stream) {
    (void)out_size; (void)ws_size;
    // Size-keyed identification; dict order: x is the FIRST 4.2M buffer.
    const float *x = nullptr, *x1 = nullptr, *wqkv = nullptr, *wout = nullptr, *bias = nullptr;
    for (int i = 0; i < n_in; ++i) {
        const int sz = in_sizes[i];
        const float* p = (const float*)d_in[i];
        if (sz == 4194304)      { if (!x) x = p; else x1 = p; }
        else if (sz == 3145728) wqkv = p;
        else if (sz == 1048576) wout = p;
        else if (sz == 1024)    bias = p;
    }
    float* out = (float*)d_out;   // FP32 output (reference dtype)

    // workspace carve-up (bf16 elements); 75.5 MB
    ushort* ws      = (ushort*)d_ws;
    ushort* wqkv_t  = ws;                          // 3072*1024
    ushort* wout_t  = wqkv_t + 3072 * 1024;        // 1024*1024
    ushort* xb      = wout_t + 1024 * 1024;        // 8192*1024 (reused as obuf)
    ushort* qbuf    = xb + 8388608;                // 4*16*2048*64
    ushort* kbuf    = qbuf + 8388608;
    ushort* vbuf    = kbuf + 8388608;
    ushort* obuf    = xb;                          // alias: xb dead after qkv_gemm

    cvt_k<<<4096, 256, 0, stream>>>(x,  xb,           4194304);
    cvt_k<<<4096, 256, 0, stream>>>(x1, xb + 4194304, 4194304);
    transpose_cvt<<<dim3(96, 32), dim3(32, 8), 0, stream>>>(wqkv, wqkv_t, 1024, 3072);
    transpose_cvt<<<dim3(32, 32), dim3(32, 8), 0, stream>>>(wout, wout_t, 1024, 1024);
    qkv_gemm<<<dim3(24, 64), 256, 0, stream>>>(xb, wqkv_t, qbuf, kbuf, vbuf);
    attn_k<<<1024, 256, 0, stream>>>(qbuf, kbuf, vbuf, obuf);
    out_gemm<<<dim3(8, 64), 256, 0, stream>>>(obuf, wout_t, bias, out);
}

// Round 2
// 306.561 us; speedup vs baseline: 2.2064x; 1.0466x over previous
//
#include <hip/hip_runtime.h>
#include <hip/hip_bf16.h>

// ---------------------------------------------------------------------------
// Cross-attention, b=2, n=2048, dim=1024, H=16, Dh=64. fp32 in, fp32 out.
// Pipeline: fp32->bf16 convert -> QKV MFMA GEMM (+Q/K/V^T scatter, Q pre-
// scaled by 1/8) -> MFMA flash attn (LDS-staged KV, double-buffered) ->
// out-proj MFMA GEMM -> fp32 store.
// Row layout: row = (s*2+b)*2048 + pos; s=0 half = out (slot 0).
//
// R2: both GEMMs ported to the m97 structure: BK=64, global_load_lds w=16
// staging (linear LDS dest, XOR-pre-swizzled global source), swizzled
// ds_read_b128 fragments (conflict-free), 2-barrier K-loop. attn unchanged.
// ---------------------------------------------------------------------------

typedef __attribute__((ext_vector_type(8))) short short8;   // 8 bf16 = 4 VGPR
typedef __attribute__((ext_vector_type(4))) float f32x4;    // MFMA 16x16 C/D

#define MFMA_BF16(a, b, c) __builtin_amdgcn_mfma_f32_16x16x32_bf16((a), (b), (c), 0, 0, 0)

__device__ __forceinline__ ushort f2bf(float f) {
    __hip_bfloat16 h = __float2bfloat16(f);
    return *reinterpret_cast<ushort*>(&h);
}

__device__ __forceinline__ void gload_lds16(const void* g, void* l) {
    __builtin_amdgcn_global_load_lds(
        (const __attribute__((address_space(1))) void*)g,
        (__attribute__((address_space(3))) void*)l, 16, 0, 0);
}

// ---------------------------------------------------------------------------
// fp32 -> bf16 convert, both inputs in one launch. 4 elems/thread.
// ---------------------------------------------------------------------------
__global__ __launch_bounds__(256) void cvt2_k(const float* __restrict__ a,
                                              const float* __restrict__ b,
                                              ushort* __restrict__ out) {
    const int idx = blockIdx.x * 256 + threadIdx.x;   // one float4 per thread
    const int half = 1048576;                          // 4194304 / 4
    const float* src = (idx < half) ? a : b;
    const int i = (idx < half ? idx : idx - half) * 4;
    float4 v = *(const float4*)(src + i);
    ushort4 o;
    o.x = f2bf(v.x); o.y = f2bf(v.y); o.z = f2bf(v.z); o.w = f2bf(v.w);
    *(ushort4*)(out + (size_t)idx * 4) = o;
}

// ---------------------------------------------------------------------------
// fp32 transpose+convert  in[R][C] -> bf16 out[C][R]  (32x32 tiles)
// ---------------------------------------------------------------------------
__global__ __launch_bounds__(256) void transpose_cvt(const float* __restrict__ in,
                                                     ushort* __restrict__ out,
                                                     int R, int C) {
    __shared__ ushort tile[32][33];
    const int c0 = blockIdx.x * 32, r0 = blockIdx.y * 32;
    const int tx = threadIdx.x, ty = threadIdx.y;   // (32, 8)
#pragma unroll
    for (int i = 0; i < 4; ++i)
        tile[ty * 4 + i][tx] = f2bf(in[(size_t)(r0 + ty * 4 + i) * C + c0 + tx]);
    __syncthreads();
#pragma unroll
    for (int i = 0; i < 4; ++i)
        out[(size_t)(c0 + ty * 4 + i) * R + r0 + tx] = tile[tx][ty * 4 + i];
}

// ---------------------------------------------------------------------------
// QKV GEMM (m97 structure).  C[8192][3072] = Xb[8192][1024] @ Wqkv^T-rows.
// BK=64, global_load_lds w=16, swizzled LDS (linear dest + pre-swizzled src,
// same XOR on ds_read). grid (24, 64), 256 threads, tile 128x128.
// Epilogue scatters: Q (pre-scaled 1/8), K -> [sb][h][n][64],
//                    V -> [sb][h][64][n] (transposed).
// ---------------------------------------------------------------------------
__global__ __launch_bounds__(256) void qkv_gemm(const ushort* __restrict__ xb,
                                                const ushort* __restrict__ wt,
                                                ushort* __restrict__ qb,
                                                ushort* __restrict__ kb,
                                                ushort* __restrict__ vb) {
    __shared__ __align__(16) ushort As[128 * 64];   // 16 KB, 128B rows, swizzled
    __shared__ __align__(16) ushort Bs[128 * 64];

    const int n0 = blockIdx.x * 128;
    const int m0 = blockIdx.y * 128;
    const int t = threadIdx.x;
    const int lane = t & 63, w = t >> 6;
    const int wm = (w >> 1) * 64, wn = (w & 1) * 64;
    const int l16 = lane & 15, lq = lane >> 4;

    // staging: 1KB chunk ch covers LDS rows ch*8..ch*8+7; lane -> row
    // ch*8 + (lane>>3); dest linear (lane*16), src col-byte XOR-swizzled.
    const int srow = lane >> 3;                          // == row & 7
    const int scol = ((lane & 7) * 16) ^ (srow << 4);    // src byte within 128B row

    f32x4 acc[4][4] = {};

    for (int k0 = 0; k0 < 1024; k0 += 64) {
        __syncthreads();                                  // readers of prev tile done
#pragma unroll
        for (int c = 0; c < 4; ++c) {
            const int ch = w * 4 + c;
            const int row = ch * 8 + srow;
            gload_lds16((const char*)xb + ((size_t)(m0 + row) * 1024 + k0) * 2 + scol,
                        (char*)As + ch * 1024);
            gload_lds16((const char*)wt + ((size_t)(n0 + row) * 1024 + k0) * 2 + scol,
                        (char*)Bs + ch * 1024);
        }
        __syncthreads();                                  // drains vmcnt(0): tile ready
#pragma unroll
        for (int kc = 0; kc < 2; ++kc) {
            short8 a[4], b[4];
#pragma unroll
            for (int i = 0; i < 4; ++i) {
                const int row = wm + i * 16 + l16;
                a[i] = *(const short8*)((const char*)As + row * 128 +
                                        ((kc * 64 + lq * 16) ^ ((row & 7) << 4)));
            }
#pragma unroll
            for (int j = 0; j < 4; ++j) {
                const int row = wn + j * 16 + l16;
                b[j] = *(const short8*)((const char*)Bs + row * 128 +
                                        ((kc * 64 + lq * 16) ^ ((row & 7) << 4)));
            }
#pragma unroll
            for (int i = 0; i < 4; ++i)
#pragma unroll
                for (int j = 0; j < 4; ++j) acc[i][j] = MFMA_BF16(a[i], b[j], acc[i][j]);
        }
    }

    const int which = (n0 >> 10);           // block-uniform: 0=Q 1=K 2=V
    const float qscale = (which == 0) ? 0.125f : 1.0f;

#pragma unroll
    for (int i = 0; i < 4; ++i) {
#pragma unroll
        for (int jj = 0; jj < 4; ++jj) {
#pragma unroll
            for (int rr = 0; rr < 4; ++rr) {
                const int m = m0 + wm + i * 16 + lq * 4 + rr;   // 0..8191
                const int nc = n0 + wn + jj * 16 + l16;         // 0..3071
                const ushort bv = f2bf(acc[i][jj][rr] * qscale);
                const int s = m >> 12;          // 0 = x-half, 1 = x1-half
                const int mm = m & 4095;        // b*2048+pos
                const int rem = nc & 1023;
                const int h = rem >> 6, d = rem & 63;
                const int sb = (s << 1) | (mm >> 11);
                const int pos = mm & 2047;
                const size_t bh = (size_t)(sb * 16 + h);
                if (which == 0)      qb[(bh * 2048 + pos) * 64 + d] = bv;
                else if (which == 1) kb[(bh * 2048 + pos) * 64 + d] = bv;
                else                 vb[(bh * 64 + d) * 2048 + pos] = bv;
            }
        }
    }
}

// ---------------------------------------------------------------------------
// MFMA flash cross-attention v2 (unchanged from R1 — verified, 0 conflicts).
// grid 1024 (remapped to (qt,h,sb)), 256 threads (4 waves). Block owns 128
// q-rows (wave: 32). KVBLK=64. K/V^T tiles staged to LDS, double-buffered,
// global_load_lds w=16 with XOR-swizzled source.
// ---------------------------------------------------------------------------
__global__ __launch_bounds__(256, 4) void attn_k(const ushort* __restrict__ qb,
                                                 const ushort* __restrict__ kb,
                                                 const ushort* __restrict__ vb,
                                                 ushort* __restrict__ ob) {
    __shared__ __align__(16) ushort Ks[2][4096];   // 2 x 8KB  (64 rows x 128B)
    __shared__ __align__(16) ushort Vs[2][4096];   // 2 x 8KB  (V^T: 64 d-rows x 128B)
    __shared__ __align__(16) ushort Pt[4][1024];   // per-wave 16x64 bf16, swizzled

    const int t = threadIdx.x, lane = t & 63, w = t >> 6;
    const int l16 = lane & 15, lq = lane >> 4;

    // XCD-locality remap: all 16 q-tiles of one (h,sb) on one XCD (lid%8).
    const int lid = blockIdx.x;                 // 0..1023
    const int xcd = lid & 7, kk = lid >> 3;     // kk: 0..127
    const int qt = kk & 15;
    const int g = xcd + ((kk >> 4) << 3);       // kv-group 0..63
    const int h = g & 15, sb = g >> 4;
    const int s = sb >> 1, bb = sb & 1;
    const int kvsb = ((1 - s) << 1) | bb;
    const int q0 = qt * 128 + w * 32;

    const ushort* qp = qb + (size_t)(sb * 16 + h) * 2048 * 64;
    const char* kp = (const char*)(kb + (size_t)(kvsb * 16 + h) * 2048 * 64);
    const char* vp = (const char*)(vb + (size_t)(kvsb * 16 + h) * 64 * 2048);

    // Q fragments: 2 q-subtiles x 2 K-chunks (Q pre-scaled by 1/8 upstream)
    short8 aq[2][2];
#pragma unroll
    for (int u = 0; u < 2; ++u)
#pragma unroll
        for (int c = 0; c < 2; ++c)
            aq[u][c] = *(const short8*)(qp + (size_t)(q0 + u * 16 + l16) * 64 + c * 32 + lq * 8);

    short8 ones;
#pragma unroll
    for (int j = 0; j < 8; ++j) ones[j] = (short)0x3F80;   // bf16 1.0

    f32x4 o_acc[2][4] = {};   // [u][dt]: row=lq*4+r (q), col=dt*16+l16 (d)
    f32x4 l_acc[2] = {};      // [u]: row sums

    const int swl = ((lane >> 3) & 7) << 4;           // (row&7)<<4 for this lane
    auto stage = [&](int buf, int key0) {
#pragma unroll
        for (int i = 0; i < 2; ++i) {
            const int ch = w * 2 + i;                  // 1KB chunk 0..7
            const int off = ch * 1024 + lane * 16;     // linear LDS byte offset
            gload_lds16(kp + (size_t)key0 * 128 + (off ^ swl),
                        (char*)&Ks[buf][0] + ch * 1024);
            const int rd = ch * 8 + (lane >> 3);       // V^T d-row 0..63
            const int cb = (lane & 7) * 16;            // col byte within row
            gload_lds16(vp + (size_t)rd * 4096 + (size_t)key0 * 2 + (cb ^ swl),
                        (char*)&Vs[buf][0] + ch * 1024);
        }
    };

    stage(0, 0);
    __syncthreads();   // implicit vmcnt(0) drain before barrier

    char* Pw = (char*)&Pt[w][0];

    for (int tt = 0; tt < 32; ++tt) {
        const int cur = tt & 1;
        if (tt < 31) stage(cur ^ 1, (tt + 1) * 64);   // overlap with compute

        const char* Kc = (const char*)&Ks[cur][0];
        const char* Vc = (const char*)&Vs[cur][0];

        // QK^T: 4 key-subtiles x 2 q-subtiles
        f32x4 sc0[4] = {}, sc1[4] = {};
#pragma unroll
        for (int j = 0; j < 4; ++j) {
            const int row = j * 16 + l16;
            const int swr = (row & 7) << 4;
            short8 k0 = *(const short8*)(Kc + row * 128 + ((lq * 16) ^ swr));
            short8 k1 = *(const short8*)(Kc + row * 128 + ((64 + lq * 16) ^ swr));
            sc0[j] = MFMA_BF16(aq[0][0], k0, sc0[j]);
            sc0[j] = MFMA_BF16(aq[0][1], k1, sc0[j]);
            sc1[j] = MFMA_BF16(aq[1][0], k0, sc1[j]);
            sc1[j] = MFMA_BF16(aq[1][1], k1, sc1[j]);
        }

        short8 ap[2][2];
        // q-subtile 0: p = exp(s) -> swizzled P-LDS -> A-frag read
#pragma unroll
        for (int j = 0; j < 4; ++j)
#pragma unroll
            for (int r2 = 0; r2 < 4; ++r2) {
                const int row = lq * 4 + r2;
                *(ushort*)(Pw + row * 128 + ((j * 32 + l16 * 2) ^ ((row & 7) << 4))) =
                    f2bf(__expf(sc0[j][r2]));
            }
        asm volatile("s_waitcnt lgkmcnt(0)" ::: "memory");   // same-wave RAW
        {
            const int swr = (l16 & 7) << 4;
            ap[0][0] = *(const short8*)(Pw + l16 * 128 + ((lq * 16) ^ swr));
            ap[0][1] = *(const short8*)(Pw + l16 * 128 + ((64 + lq * 16) ^ swr));
        }
        asm volatile("s_waitcnt lgkmcnt(0)" ::: "memory");   // reads landed (WAR safety)
        // q-subtile 1 reuses the same P scratch
#pragma unroll
        for (int j = 0; j < 4; ++j)
#pragma unroll
            for (int r2 = 0; r2 < 4; ++r2) {
                const int row = lq * 4 + r2;
                *(ushort*)(Pw + row * 128 + ((j * 32 + l16 * 2) ^ ((row & 7) << 4))) =
                    f2bf(__expf(sc1[j][r2]));
            }
        asm volatile("s_waitcnt lgkmcnt(0)" ::: "memory");
        {
            const int swr = (l16 & 7) << 4;
            ap[1][0] = *(const short8*)(Pw + l16 * 128 + ((lq * 16) ^ swr));
            ap[1][1] = *(const short8*)(Pw + l16 * 128 + ((64 + lq * 16) ^ swr));
        }

        l_acc[0] = MFMA_BF16(ap[0][0], ones, l_acc[0]);
        l_acc[0] = MFMA_BF16(ap[0][1], ones, l_acc[0]);
        l_acc[1] = MFMA_BF16(ap[1][0], ones, l_acc[1]);
        l_acc[1] = MFMA_BF16(ap[1][1], ones, l_acc[1]);
#pragma unroll
        for (int dt = 0; dt < 4; ++dt) {
            const int row = dt * 16 + l16;
            const int swr = (row & 7) << 4;
            short8 v0 = *(const short8*)(Vc + row * 128 + ((lq * 16) ^ swr));
            short8 v1 = *(const short8*)(Vc + row * 128 + ((64 + lq * 16) ^ swr));
            o_acc[0][dt] = MFMA_BF16(ap[0][0], v0, o_acc[0][dt]);
            o_acc[0][dt] = MFMA_BF16(ap[0][1], v1, o_acc[0][dt]);
            o_acc[1][dt] = MFMA_BF16(ap[1][0], v0, o_acc[1][dt]);
            o_acc[1][dt] = MFMA_BF16(ap[1][1], v1, o_acc[1][dt]);
        }

        __syncthreads();   // drains vmcnt(0): next tile staged + frag reads done
    }

#pragma unroll
    for (int u = 0; u < 2; ++u) {
        float inv[4];
#pragma unroll
        for (int r2 = 0; r2 < 4; ++r2) inv[r2] = 1.f / l_acc[u][r2];
#pragma unroll
        for (int dt = 0; dt < 4; ++dt)
#pragma unroll
            for (int r2 = 0; r2 < 4; ++r2)
                ob[(size_t)(sb * 2048 + q0 + u * 16 + lq * 4 + r2) * 1024 + h * 64 + dt * 16 + l16] =
                    f2bf(o_acc[u][dt][r2] * inv[r2]);
    }
}

// ---------------------------------------------------------------------------
// Out projection (m97 structure). OUT[8192][1024] = O[8192][1024] @ Wout + b.
// BK=64, global_load_lds w=16, swizzled LDS. FP32 stores. grid (8, 64).
// ---------------------------------------------------------------------------
__global__ __launch_bounds__(256) void out_gemm(const ushort* __restrict__ ob,
                                                const ushort* __restrict__ wot,
                                                const float* __restrict__ bias,
                                                float* __restrict__ out) {
    __shared__ __align__(16) ushort As[128 * 64];
    __shared__ __align__(16) ushort Bs[128 * 64];

    const int n0 = blockIdx.x * 128;
    const int m0 = blockIdx.y * 128;
    const int t = threadIdx.x;
    const int lane = t & 63, w = t >> 6;
    const int wm = (w >> 1) * 64, wn = (w & 1) * 64;
    const int l16 = lane & 15, lq = lane >> 4;

    const int srow = lane >> 3;
    const int scol = ((lane & 7) * 16) ^ (srow << 4);

    f32x4 acc[4][4] = {};

    for (int k0 = 0; k0 < 1024; k0 += 64) {
        __syncthreads();
#pragma unroll
        for (int c = 0; c < 4; ++c) {
            const int ch = w * 4 + c;
            const int row = ch * 8 + srow;
            gload_lds16((const char*)ob + ((size_t)(m0 + row) * 1024 + k0) * 2 + scol,
                        (char*)As + ch * 1024);
            gload_lds16((const char*)wot + ((size_t)(n0 + row) * 1024 + k0) * 2 + scol,
                        (char*)Bs + ch * 1024);
        }
        __syncthreads();
#pragma unroll
        for (int kc = 0; kc < 2; ++kc) {
            short8 a[4], b[4];
#pragma unroll
            for (int i = 0; i < 4; ++i) {
                const int row = wm + i * 16 + l16;
                a[i] = *(const short8*)((const char*)As + row * 128 +
                                        ((kc * 64 + lq * 16) ^ ((row & 7) << 4)));
            }
#pragma unroll
            for (int j = 0; j < 4; ++j) {
                const int row = wn + j * 16 + l16;
                b[j] = *(const short8*)((const char*)Bs + row * 128 +
                                        ((kc * 64 + lq * 16) ^ ((row & 7) << 4)));
            }
#pragma unroll
            for (int i = 0; i < 4; ++i)
#pragma unroll
                for (int j = 0; j < 4; ++j) acc[i][j] = MFMA_BF16(a[i], b[j], acc[i][j]);
        }
    }

    float biasf[4];
#pragma unroll
    for (int jj = 0; jj < 4; ++jj) biasf[jj] = bias[n0 + wn + jj * 16 + l16];

#pragma unroll
    for (int i = 0; i < 4; ++i)
#pragma unroll
        for (int jj = 0; jj < 4; ++jj)
#pragma unroll
            for (int rr = 0; rr < 4; ++rr) {
                const int m = m0 + wm + i * 16 + lq * 4 + rr;
                const int nc = n0 + wn + jj * 16 + l16;
                out[(size_t)m * 1024 + nc] = acc[i][jj][rr] + biasf[jj];   // fp32 store
            }
}

// ---------------------------------------------------------------------------
extern "C" void kernel_launch(void* const* d_in, const int* in_sizes, int n_in,
                              void* d_out, int out_size, void* d_ws, size_t ws_size,
                              hipStream_t stream) {
    (void)out_size; (void)ws_size;
    // Size-keyed identification; dict order: x is the FIRST 4.2M buffer.
    const float *x = nullptr, *x1 = nullptr, *wqkv = nullptr, *wout = nullptr, *bias = nullptr;
    for (int i = 0; i < n_in; ++i) {
        const int sz = in_sizes[i];
        const float* p = (const float*)d_in[i];
        if (sz == 4194304)      { if (!x) x = p; else x1 = p; }
        else if (sz == 3145728) wqkv = p;
        else if (sz == 1048576) wout = p;
        else if (sz == 1024)    bias = p;
    }
    float* out = (float*)d_out;   // FP32 output (reference dtype)

    // workspace carve-up (bf16 elements); 75.5 MB
    ushort* ws      = (ushort*)d_ws;
    ushort* wqkv_t  = ws;                          // 3072*1024
    ushort* wout_t  = wqkv_t + 3072 * 1024;        // 1024*1024
    ushort* xb      = wout_t + 1024 * 1024;        // 8192*1024 (reused as obuf)
    ushort* qbuf    = xb + 8388608;                // 4*16*2048*64
    ushort* kbuf    = qbuf + 8388608;
    ushort* vbuf    = kbuf + 8388608;
    ushort* obuf    = xb;                          // alias: xb dead after qkv_gemm

    cvt2_k<<<8192, 256, 0, stream>>>(x, x1, xb);
    transpose_cvt<<<dim3(96, 32), dim3(32, 8), 0, stream>>>(wqkv, wqkv_t, 1024, 3072);
    transpose_cvt<<<dim3(32, 32), dim3(32, 8), 0, stream>>>(wout, wout_t, 1024, 1024);
    qkv_gemm<<<dim3(24, 64), 256, 0, stream>>>(xb, wqkv_t, qbuf, kbuf, vbuf);
    attn_k<<<1024, 256, 0, stream>>>(qbuf, kbuf, vbuf, obuf);
    out_gemm<<<dim3(8, 64), 256, 0, stream>>>(obuf, wout_t, bias, out);
}